// Round 10
// baseline (245.099 us; speedup 1.0000x reference)
//
#include <hip/hip_runtime.h>

#define H 128
#define EPS 1e-12f
#define NBLK 256      // partition blocks for hist/scatter
#define NB_MAX 12544  // max buckets in LDS (49 KB)

typedef unsigned long long u64;

static __device__ __forceinline__ float bf_lo(unsigned int v) {
    return __uint_as_float(v << 16);
}
static __device__ __forceinline__ float bf_hi(unsigned int v) {
    return __uint_as_float(v & 0xFFFF0000u);
}
static __device__ __forceinline__ unsigned int f2bf_rne(float f) {
    unsigned int u = __float_as_uint(f);
    return (u + 0x7FFFu + ((u >> 16) & 1u)) >> 16;
}

static __device__ __forceinline__ float dot8(uint4 a, uint4 b,
                                             float4 d0, float4 d1, float p) {
    p = fmaf(bf_lo(a.x) * d0.x, bf_lo(b.x), p);
    p = fmaf(bf_hi(a.x) * d0.y, bf_hi(b.x), p);
    p = fmaf(bf_lo(a.y) * d0.z, bf_lo(b.y), p);
    p = fmaf(bf_hi(a.y) * d0.w, bf_hi(b.y), p);
    p = fmaf(bf_lo(a.z) * d1.x, bf_lo(b.z), p);
    p = fmaf(bf_hi(a.z) * d1.y, bf_hi(b.z), p);
    p = fmaf(bf_lo(a.w) * d1.z, bf_lo(b.w), p);
    p = fmaf(bf_hi(a.w) * d1.w, bf_hi(b.w), p);
    return p;
}

// Normalize rows, quantize to bf16, 256B/row pool (row-major).
__global__ void norm_quant_kernel(const float* __restrict__ emb,
                                  unsigned int* __restrict__ pool,
                                  int n_nodes) {
    int row = blockIdx.x * (blockDim.x >> 6) + (threadIdx.x >> 6);
    if (row >= n_nodes) return;
    int lane = threadIdx.x & 63;
    const float* p = emb + (size_t)row * H + lane * 2;
    float vx = __builtin_nontemporal_load(p);
    float vy = __builtin_nontemporal_load(p + 1);
    float ss = vx * vx + vy * vy;
#pragma unroll
    for (int off = 32; off; off >>= 1) ss += __shfl_xor(ss, off);
    float inv = 1.0f / fmaxf(sqrtf(ss), EPS);
    pool[(size_t)row * 64 + lane] =
        f2bf_rne(vx * inv) | (f2bf_rne(vy * inv) << 16);
}

// ---- 2-level deterministic bucket sort: key = (src/gdiv)*nbd + (dst>>6) ----

__global__ void hist2_kernel(const int* __restrict__ src,
                             const int* __restrict__ dst,
                             unsigned int* __restrict__ M,  // [NBLK][nb]
                             int n_edges, int nb, int nbd, int gdiv) {
    __shared__ unsigned int cnt[NB_MAX];
    for (int b = threadIdx.x; b < nb; b += blockDim.x) cnt[b] = 0;
    __syncthreads();
    int ce = (n_edges + NBLK - 1) / NBLK;
    int lo = blockIdx.x * ce;
    int hi = min(lo + ce, n_edges);
    for (int e = lo + (int)threadIdx.x; e < hi; e += blockDim.x) {
        int s = __builtin_nontemporal_load(src + e);
        int t = __builtin_nontemporal_load(dst + e);
        int key = (s / gdiv) * nbd + (int)(((unsigned)t) >> 6);
        atomicAdd(&cnt[key], 1u);
    }
    __syncthreads();
    unsigned int* row = M + (size_t)blockIdx.x * nb;
    for (int b = threadIdx.x; b < nb; b += blockDim.x) row[b] = cnt[b];
}

// One wave per bucket: exclusive prefix over the NBLK=256 block-counts
// (4 chunks of 64 via shuffle scan), in place; bucket total -> total[b].
__global__ void prefixM_kernel(unsigned int* __restrict__ M,
                               unsigned int* __restrict__ total, int nb) {
    int b = blockIdx.x * 4 + (threadIdx.x >> 6);
    if (b >= nb) return;
    int lane = threadIdx.x & 63;
    unsigned int run = 0;
    unsigned int ex[4];
#pragma unroll
    for (int k = 0; k < 4; ++k) {
        unsigned int v = M[(size_t)(k * 64 + lane) * nb + b];
        unsigned int x = v;
        for (int o = 1; o < 64; o <<= 1) {
            unsigned int tt = __shfl_up(x, o);
            if (lane >= o) x += tt;
        }
        ex[k] = run + x - v;
        run += __shfl(x, 63);
    }
#pragma unroll
    for (int k = 0; k < 4; ++k) M[(size_t)(k * 64 + lane) * nb + b] = ex[k];
    if (lane == 0) total[b] = run;
}

// single-block in-place exclusive scan over nb buckets
__global__ void scan_kernel(unsigned int* __restrict__ cur, int nb) {
    __shared__ unsigned int part[256];
    int t = threadIdx.x;
    int chunk = (nb + 255) / 256;
    int lo = t * chunk;
    int hi = lo + chunk < nb ? lo + chunk : nb;
    unsigned int sum = 0;
    for (int i = lo; i < hi; ++i) sum += cur[i];
    part[t] = sum;
    __syncthreads();
    if (t == 0) {
        unsigned int acc = 0;
        for (int i = 0; i < 256; ++i) {
            unsigned int v = part[i];
            part[i] = acc;
            acc += v;
        }
    }
    __syncthreads();
    unsigned int acc = part[t];
    for (int i = lo; i < hi; ++i) {
        unsigned int v = cur[i];
        cur[i] = acc;
        acc += v;
    }
}

// Scatter packed u64 records with LDS cursors (cur = M[blk][b] + base[b]).
__global__ void scatter2_kernel(const int* __restrict__ src,
                                const int* __restrict__ dst,
                                const unsigned int* __restrict__ M,
                                const unsigned int* __restrict__ base,
                                u64* __restrict__ sorted,
                                int n_edges, int nb, int nbd, int gdiv) {
    __shared__ unsigned int cur[NB_MAX];
    const unsigned int* row = M + (size_t)blockIdx.x * nb;
    for (int b = threadIdx.x; b < nb; b += blockDim.x)
        cur[b] = row[b] + base[b];
    __syncthreads();
    int ce = (n_edges + NBLK - 1) / NBLK;
    int lo = blockIdx.x * ce;
    int hi = min(lo + ce, n_edges);
    for (int e = lo + (int)threadIdx.x; e < hi; e += blockDim.x) {
        int s = __builtin_nontemporal_load(src + e);
        int t = __builtin_nontemporal_load(dst + e);
        int key = (s / gdiv) * nbd + (int)(((unsigned)t) >> 6);
        unsigned int pos = atomicAdd(&cur[key], 1u);
        u64 rec = (u64)(unsigned)s | ((u64)(unsigned)t << 17) |
                  ((u64)(unsigned)e << 34);
        sorted[pos] = rec;
    }
}

// Block b: group g=b&7 (XCD-pinned under %8 round-robin), dst-bucket slice
// i=b>>3. src gathers confined to group's 3.2MB window (XCD-L2-resident);
// dst gathers confined to slice's ~98KB window (dst-sorted sweep).
__global__ void edge_dot_2lvl_kernel(const uint4* __restrict__ pool,
                                     const u64* __restrict__ sorted,
                                     const unsigned int* __restrict__ base,
                                     const float* __restrict__ d,
                                     const float* __restrict__ scale,
                                     float* __restrict__ out,
                                     int n_edges, int nb, int nbd) {
    int g = blockIdx.x & 7;
    int i = blockIdx.x >> 3;
    int nslice = gridDim.x >> 3;
    int b_lo = g * nbd + (int)((long long)i * nbd / nslice);
    int b_hi = g * nbd + (int)((long long)(i + 1) * nbd / nslice);
    int e_lo = (int)base[b_lo];
    int e_hi = (b_hi >= nb) ? n_edges : (int)base[b_hi];

    int lane = threadIdx.x & 63;
    int wave = threadIdx.x >> 6;  // 0..3
    int sub  = lane >> 3;
    int q    = lane & 7;

    float4 dv0 = ((const float4*)d)[q * 4 + 0];
    float4 dv1 = ((const float4*)d)[q * 4 + 1];
    float4 dv2 = ((const float4*)d)[q * 4 + 2];
    float4 dv3 = ((const float4*)d)[q * 4 + 3];
    float sc = scale[0];

    for (int eb = e_lo + wave * 16; eb < e_hi; eb += 64) {
        int e0 = eb + sub;
        int e1 = eb + 8 + sub;
        bool w0 = (e0 < e_hi);
        bool w1 = (e1 < e_hi);
        int c0 = w0 ? e0 : e_hi - 1;
        int c1 = w1 ? e1 : e_hi - 1;

        u64 r0 = __builtin_nontemporal_load(sorted + c0);
        u64 r1 = __builtin_nontemporal_load(sorted + c1);
        int s0 = (int)(r0 & 0x1FFFF);
        int t0 = (int)((r0 >> 17) & 0x1FFFF);
        int i0 = (int)(r0 >> 34);
        int s1 = (int)(r1 & 0x1FFFF);
        int t1 = (int)((r1 >> 17) & 0x1FFFF);
        int i1 = (int)(r1 >> 34);

        const uint4* pa0 = pool + (size_t)s0 * 16 + q * 2;
        const uint4* pb0 = pool + (size_t)t0 * 16 + q * 2;
        const uint4* pa1 = pool + (size_t)s1 * 16 + q * 2;
        const uint4* pb1 = pool + (size_t)t1 * 16 + q * 2;
        uint4 a00 = pa0[0];
        uint4 a01 = pa0[1];
        uint4 b00 = pb0[0];
        uint4 b01 = pb0[1];
        uint4 a10 = pa1[0];
        uint4 a11 = pa1[1];
        uint4 b10 = pb1[0];
        uint4 b11 = pb1[1];

        float p0 = dot8(a00, b00, dv0, dv1, 0.0f);
        p0 = dot8(a01, b01, dv2, dv3, p0);
        float p1 = dot8(a10, b10, dv0, dv1, 0.0f);
        p1 = dot8(a11, b11, dv2, dv3, p1);

        p0 += __shfl_xor(p0, 1);
        p1 += __shfl_xor(p1, 1);
        p0 += __shfl_xor(p0, 2);
        p1 += __shfl_xor(p1, 2);
        p0 += __shfl_xor(p0, 4);
        p1 += __shfl_xor(p1, 4);

        if (q == 0) {
            if (w0) out[i0] = p0 * sc;  // plain: L2 merges scattered 4B
            if (w1) out[i1] = p1 * sc;
        }
    }
}

// ---------------- R4 path (proven 124 us total) ----------------

__global__ void edge_dot_bf16_kernel(const uint4* __restrict__ pool,
                                     const int* __restrict__ src,
                                     const int* __restrict__ dst,
                                     const float* __restrict__ d,
                                     const float* __restrict__ scale,
                                     float* __restrict__ out,
                                     int n_edges) {
    int lane = threadIdx.x & 63;
    int sub  = lane >> 3;
    int q    = lane & 7;

    float4 dv0 = ((const float4*)d)[q * 4 + 0];
    float4 dv1 = ((const float4*)d)[q * 4 + 1];
    float4 dv2 = ((const float4*)d)[q * 4 + 2];
    float4 dv3 = ((const float4*)d)[q * 4 + 3];
    float sc = scale[0];

    int waveId = (blockIdx.x * blockDim.x + threadIdx.x) >> 6;
    int nWaves = (gridDim.x * blockDim.x) >> 6;
    int last = n_edges - 1;

    for (int ebase = waveId * 16; ebase < n_edges; ebase += nWaves * 16) {
        int e0 = ebase + sub;
        int e1 = ebase + 8 + sub;
        bool w0 = (e0 < n_edges);
        bool w1 = (e1 < n_edges);
        int c0 = w0 ? e0 : last;
        int c1 = w1 ? e1 : last;

        int s0 = __builtin_nontemporal_load(src + c0);
        int t0 = __builtin_nontemporal_load(dst + c0);
        int s1 = __builtin_nontemporal_load(src + c1);
        int t1 = __builtin_nontemporal_load(dst + c1);

        const uint4* pa0 = pool + (size_t)s0 * 16 + q * 2;
        const uint4* pb0 = pool + (size_t)t0 * 16 + q * 2;
        const uint4* pa1 = pool + (size_t)s1 * 16 + q * 2;
        const uint4* pb1 = pool + (size_t)t1 * 16 + q * 2;
        uint4 a00 = pa0[0];
        uint4 a01 = pa0[1];
        uint4 b00 = pb0[0];
        uint4 b01 = pb0[1];
        uint4 a10 = pa1[0];
        uint4 a11 = pa1[1];
        uint4 b10 = pb1[0];
        uint4 b11 = pb1[1];

        float p0 = dot8(a00, b00, dv0, dv1, 0.0f);
        p0 = dot8(a01, b01, dv2, dv3, p0);
        float p1 = dot8(a10, b10, dv0, dv1, 0.0f);
        p1 = dot8(a11, b11, dv2, dv3, p1);

        p0 += __shfl_xor(p0, 1);
        p1 += __shfl_xor(p1, 1);
        p0 += __shfl_xor(p0, 2);
        p1 += __shfl_xor(p1, 2);
        p0 += __shfl_xor(p0, 4);
        p1 += __shfl_xor(p1, 4);

        if (q == 0) {
            if (w0) __builtin_nontemporal_store(p0 * sc, out + e0);
            if (w1) __builtin_nontemporal_store(p1 * sc, out + e1);
        }
    }
}

// ---------------- fallback f32 path (proven R1) ----------------

__global__ void inv_norm_kernel(const float* __restrict__ emb,
                                float* __restrict__ inv,
                                int n_nodes) {
    int row = blockIdx.x * (blockDim.x >> 6) + (threadIdx.x >> 6);
    if (row >= n_nodes) return;
    int lane = threadIdx.x & 63;
    const float2* p = (const float2*)(emb + (size_t)row * H);
    float2 v = p[lane];
    float ss = v.x * v.x + v.y * v.y;
#pragma unroll
    for (int off = 32; off; off >>= 1) ss += __shfl_xor(ss, off);
    if (lane == 0) inv[row] = 1.0f / fmaxf(sqrtf(ss), EPS);
}

__global__ void edge_dot_kernel(const float* __restrict__ emb,
                                const float* __restrict__ inv,
                                const int* __restrict__ src,
                                const int* __restrict__ dst,
                                const float* __restrict__ d,
                                const float* __restrict__ scale,
                                float* __restrict__ out,
                                int n_edges) {
    int edge = blockIdx.x * (blockDim.x >> 6) + (threadIdx.x >> 6);
    if (edge >= n_edges) return;
    int lane = threadIdx.x & 63;
    int s = src[edge];
    int t = dst[edge];
    const float2* ps = (const float2*)(emb + (size_t)s * H);
    const float2* pt = (const float2*)(emb + (size_t)t * H);
    float2 dv = ((const float2*)d)[lane];
    float2 a = ps[lane];
    float2 b = pt[lane];
    float p = a.x * dv.x * b.x + a.y * dv.y * b.y;
#pragma unroll
    for (int off = 32; off; off >>= 1) p += __shfl_xor(p, off);
    if (lane == 0) out[edge] = p * inv[s] * inv[t] * scale[0];
}

extern "C" void kernel_launch(void* const* d_in, const int* in_sizes, int n_in,
                              void* d_out, int out_size, void* d_ws, size_t ws_size,
                              hipStream_t stream) {
    const float* emb   = (const float*)d_in[0];
    const int*   src   = (const int*)d_in[1];
    const int*   dst   = (const int*)d_in[2];
    const float* d     = (const float*)d_in[3];
    const float* scale = (const float*)d_in[4];
    float* out = (float*)d_out;

    int n_nodes = in_sizes[0] / H;
    int n_edges = in_sizes[1];
    int nbd  = (n_nodes + 63) >> 6;       // dst buckets (64 nodes)
    int nb   = 8 * nbd;                   // 2-level key space
    int gdiv = (n_nodes + 7) / 8;         // src supergroup divisor

    size_t pool_bytes = (size_t)n_nodes * H * 2;               // 25.6 MB
    size_t sort_bytes = (size_t)n_edges * sizeof(u64);         // 12.8 MB
    size_t M_bytes    = (size_t)NBLK * nb * sizeof(unsigned);  // 12.8 MB
    size_t tot_bytes  = (size_t)nb * sizeof(unsigned);

    bool packable = (n_nodes <= (1 << 17)) && (n_edges <= (1 << 21));

    if (packable && nb <= NB_MAX &&
        ws_size >= pool_bytes + sort_bytes + M_bytes + tot_bytes) {
        unsigned int* pool   = (unsigned int*)d_ws;
        u64*          sorted = (u64*)((char*)d_ws + pool_bytes);
        unsigned int* M      = (unsigned int*)((char*)d_ws + pool_bytes + sort_bytes);
        unsigned int* base   = (unsigned int*)((char*)d_ws + pool_bytes + sort_bytes + M_bytes);

        int blocks1 = (n_nodes + 3) / 4;
        norm_quant_kernel<<<blocks1, 256, 0, stream>>>(emb, pool, n_nodes);

        hist2_kernel<<<NBLK, 256, 0, stream>>>(src, dst, M, n_edges, nb, nbd,
                                               gdiv);
        prefixM_kernel<<<(nb + 3) / 4, 256, 0, stream>>>(M, base, nb);
        scan_kernel<<<1, 256, 0, stream>>>(base, nb);
        scatter2_kernel<<<NBLK, 256, 0, stream>>>(src, dst, M, base, sorted,
                                                  n_edges, nb, nbd, gdiv);

        edge_dot_2lvl_kernel<<<2048, 256, 0, stream>>>(
            (const uint4*)pool, sorted, base, d, scale, out, n_edges, nb, nbd);
    } else if (ws_size >= pool_bytes) {
        unsigned int* pool = (unsigned int*)d_ws;
        int blocks1 = (n_nodes + 3) / 4;
        norm_quant_kernel<<<blocks1, 256, 0, stream>>>(emb, pool, n_nodes);
        edge_dot_bf16_kernel<<<2048, 256, 0, stream>>>(
            (const uint4*)pool, src, dst, d, scale, out, n_edges);
    } else {
        float* inv = (float*)d_ws;
        int blocks1 = (n_nodes + 3) / 4;
        inv_norm_kernel<<<blocks1, 256, 0, stream>>>(emb, inv, n_nodes);
        int blocks2 = (n_edges + 3) / 4;
        edge_dot_kernel<<<blocks2, 256, 0, stream>>>(emb, inv, src, dst, d,
                                                     scale, out, n_edges);
    }
}